// Round 12
// baseline (812.614 us; speedup 1.0000x reference)
//
#include <hip/hip_runtime.h>

// RGCN: 2-layer hetero GraphConv, R=4 relations.
// R1: CSR gather. R2: bf16 MFMA GEMM. R3: concat-GEMM + fused gathers.
// R4: layer-1 aggregate-first. R5 REGRESSED (reverted). R6: e_pack int2 stream.
// R7: half-wave-per-edge gathers. R8: NT-store outputs. R9/R10: rank-from-hist
// (atomic-free fill), prep+hist merged — REGRESSED: prep's 153MB stream evicted
// the atomic tables from L2. R11: NT load/store on ALL streaming paths in the
// merged kernel (sequential full-line streams only — the safe NT regime), so
// counter tables stay L2-hot while prep overlaps hist's atomic latency.

#define RELS 4
#define DIN 256
#define DHID 256
#define DOUT 128

typedef short short8 __attribute__((ext_vector_type(8)));
typedef unsigned short ushort8 __attribute__((ext_vector_type(8)));
typedef float f32x4 __attribute__((ext_vector_type(4)));

// ---- helpers --------------------------------------------------------------

__device__ __forceinline__ unsigned short f2bf(float f) {
    unsigned int u = __float_as_uint(f);
    u += 0x7FFFu + ((u >> 16) & 1u);   // round-to-nearest-even
    return (unsigned short)(u >> 16);
}
__device__ __forceinline__ float bf2f(unsigned short u) {
    return __uint_as_float(((unsigned int)u) << 16);
}

// ---- phase 1: hist (+rank) merged with prep; all streams nontemporal --------

__global__ void hist_prep(const int* __restrict__ src, const int* __restrict__ dst,
                          int* __restrict__ cnt_src, int* __restrict__ cnt_dst,
                          int* __restrict__ rank, int E, int N, int HB,
                          const float* __restrict__ x, const float* __restrict__ W1,
                          const float* __restrict__ W2, const float* __restrict__ b1,
                          const float* __restrict__ b2,
                          unsigned short* __restrict__ x_bf, unsigned short* __restrict__ w1t,
                          unsigned short* __restrict__ w2t,
                          float* __restrict__ b1s, float* __restrict__ b2s, long n8x) {
    const int T1 = RELS * DIN * DHID;
    const int T2 = RELS * DHID * DOUT;
    if ((int)blockIdx.x < HB) {
        int i = blockIdx.x * 256 + threadIdx.x;
        if (i >= RELS * E) return;
        int r = i / E;
        int s = __builtin_nontemporal_load(src + i);   // streaming: keep L2 for tables
        int d = __builtin_nontemporal_load(dst + i);
        atomicAdd(cnt_src + (size_t)r * N + s, 1);
        int rk = atomicAdd(cnt_dst + (size_t)r * N + d, 1);
        __builtin_nontemporal_store(rk, rank + i);
    } else {
        long i = (long)(blockIdx.x - HB) * 256 + threadIdx.x;
        if (i < n8x) {
            const f32x4* ip = (const f32x4*)(x + i * 8);
            f32x4 v0 = __builtin_nontemporal_load(ip);
            f32x4 v1 = __builtin_nontemporal_load(ip + 1);
            ushort8 o;
            o[0] = f2bf(v0[0]); o[1] = f2bf(v0[1]); o[2] = f2bf(v0[2]); o[3] = f2bf(v0[3]);
            o[4] = f2bf(v1[0]); o[5] = f2bf(v1[1]); o[6] = f2bf(v1[2]); o[7] = f2bf(v1[3]);
            __builtin_nontemporal_store(o, (ushort8*)(x_bf + i * 8));
        } else if (i < n8x + T1) {
            int j = (int)(i - n8x);
            int r = j / (DIN * DHID);
            int rem = j - r * (DIN * DHID);
            int k = rem / DHID, n = rem - k * DHID;
            float w = __builtin_nontemporal_load(W1 + j);
            w1t[(size_t)n * (RELS * DIN) + r * DIN + k] = f2bf(w);
        } else if (i < n8x + T1 + T2) {
            int j = (int)(i - n8x - T1);
            int r = j / (DHID * DOUT);
            int rem = j - r * (DHID * DOUT);
            int k = rem / DOUT, n = rem - k * DOUT;
            float w = __builtin_nontemporal_load(W2 + j);
            w2t[((size_t)r * DOUT + n) * DHID + k] = f2bf(w);
        } else if (i < n8x + T1 + T2 + DHID + DOUT) {
            int c = (int)(i - n8x - T1 - T2);
            if (c < DHID) {
                b1s[c] = b1[c] + b1[DHID + c] + b1[2 * DHID + c] + b1[3 * DHID + c];
            } else {
                int cc = c - DHID;
                b2s[cc] = b2[cc] + b2[DOUT + cc] + b2[2 * DOUT + cc] + b2[3 * DOUT + cc];
            }
        }
    }
}

// ---- phase 2: scan_block merged with norm (both depend only on hist) --------

__global__ void scan_norm(const int* __restrict__ counts, int* __restrict__ out,
                          int* __restrict__ blk_sums, int n, int SB,
                          const int* __restrict__ cnt, float* __restrict__ nrm, long nnorm) {
    if ((int)blockIdx.x < SB) {
        __shared__ int sh[256];
        int i = blockIdx.x * 256 + threadIdx.x;
        int v = (i < n) ? counts[i] : 0;
        sh[threadIdx.x] = v;
        __syncthreads();
#pragma unroll
        for (int off = 1; off < 256; off <<= 1) {
            int t = (threadIdx.x >= off) ? sh[threadIdx.x - off] : 0;
            __syncthreads();
            sh[threadIdx.x] += t;
            __syncthreads();
        }
        if (i < n) out[i] = sh[threadIdx.x] - v;
        if (threadIdx.x == 255) blk_sums[blockIdx.x] = sh[255];
    } else {
        long i = (long)(blockIdx.x - SB) * 256 + threadIdx.x;
        if (i < nnorm) nrm[i] = rsqrtf(fmaxf((float)cnt[i], 1.0f));
    }
}

__global__ void scan_sums(int* __restrict__ bs, int nb) {
    __shared__ int sh[256];
    __shared__ int carry;
    if (threadIdx.x == 0) carry = 0;
    __syncthreads();
    for (int base = 0; base < nb; base += 256) {
        int i = base + threadIdx.x;
        int v = (i < nb) ? bs[i] : 0;
        sh[threadIdx.x] = v;
        __syncthreads();
#pragma unroll
        for (int off = 1; off < 256; off <<= 1) {
            int t = (threadIdx.x >= off) ? sh[threadIdx.x - off] : 0;
            __syncthreads();
            sh[threadIdx.x] += t;
            __syncthreads();
        }
        if (i < nb) bs[i] = sh[threadIdx.x] - v + carry;  // exclusive
        int tot = sh[255];
        __syncthreads();
        if (threadIdx.x == 255) carry += tot;
        __syncthreads();
    }
}

__global__ void scan_add(int* __restrict__ out, const int* __restrict__ blk_sums,
                         int n, int total) {
    int i = blockIdx.x * 256 + threadIdx.x;
    if (i < n) out[i] += blk_sums[blockIdx.x];
    if (i == n - 1) out[n] = total;
}

// ---- phase 3: atomic-free fill ----------------------------------------------

// pos = row_ptr[r][dst] + rank  (rank captured during hist).
// e_pack entry packed into long long: lo32=src, hi32=ns bits.
__global__ void fill_kernel(const int* __restrict__ src, const int* __restrict__ dst,
                            const float* __restrict__ nsrc, const int* __restrict__ row_ptr,
                            const int* __restrict__ rank, long long* __restrict__ e_pack,
                            int E, int N) {
    int i = blockIdx.x * blockDim.x + threadIdx.x;
    if (i >= RELS * E) return;
    int r = i / E;
    int s = __builtin_nontemporal_load(src + i);
    int d = __builtin_nontemporal_load(dst + i);
    int rk = __builtin_nontemporal_load(rank + i);
    int pos = row_ptr[(size_t)r * N + d] + rk;
    unsigned long long v = (unsigned int)s |
        ((unsigned long long)(unsigned int)__float_as_int(nsrc[(size_t)r * N + s]) << 32);
    __builtin_nontemporal_store((long long)v, e_pack + pos);
}

// ---- bf16 MFMA GEMM ---------------------------------------------------------
// BM=BN=128, BK=32, 256 threads (4 waves 2x2), 4x4 frags of 16x16x32/wave.
// LDS [128][32] bf16 per operand, XOR chunk swizzle (both-sides involution).
// MODE 0: C = bf16( acc * nsrc[rel][row] )          (layer-2 project-first)
// MODE 1: C = bf16( relu(acc + bias[col]) )         (layer-1 agg-first)

__device__ __forceinline__ void gload_lds16(const void* g, void* l) {
    __builtin_amdgcn_global_load_lds(
        (const __attribute__((address_space(1))) void*)g,
        (__attribute__((address_space(3))) void*)l, 16, 0, 0);
}

template <int MODE>
__global__ __launch_bounds__(256) void gemm_bf16(
    const unsigned short* __restrict__ A, const unsigned short* __restrict__ Bt,
    unsigned short* __restrict__ C, int M, int Nout, int K,
    const float* __restrict__ scale_or_bias, int cols_per_rel, int Nnodes) {
    __shared__ unsigned short smA[128 * 32];
    __shared__ unsigned short smB[128 * 32];
    const int tid = threadIdx.x;
    const int lane = tid & 63;
    const int wid = tid >> 6;
    const int wr = wid >> 1, wc = wid & 1;
    const int brow = blockIdx.x * 128, bcol = blockIdx.y * 128;

    f32x4 acc[4][4] = {};

    const int s = lane >> 4;
    const int rl = lane & 15;

    for (int k0 = 0; k0 < K; k0 += 32) {
#pragma unroll
        for (int q = 0; q < 2; ++q) {
            int c = q * 256 + tid;
            int cl = c ^ ((c >> 3) & 3);
            int row = cl >> 2, slot = cl & 3;
            int ga = brow + row; ga = ga < M ? ga : M - 1;
            size_t ldsoff = (size_t)(q * 256 + (tid & ~63)) * 16;
            gload_lds16(A + (size_t)ga * K + k0 + slot * 8, (char*)smA + ldsoff);
            gload_lds16(Bt + (size_t)(bcol + row) * K + k0 + slot * 8, (char*)smB + ldsoff);
        }
        asm volatile("s_waitcnt vmcnt(0)" ::: "memory");
        __syncthreads();

        short8 a[4], b[4];
#pragma unroll
        for (int i = 0; i < 4; ++i) {
            int r = wr * 64 + i * 16 + rl;
            int ch = r * 4 + (s ^ ((r >> 1) & 3));
            a[i] = *(const short8*)((const char*)smA + ch * 16);
        }
#pragma unroll
        for (int j = 0; j < 4; ++j) {
            int r = wc * 64 + j * 16 + rl;
            int ch = r * 4 + (s ^ ((r >> 1) & 3));
            b[j] = *(const short8*)((const char*)smB + ch * 16);
        }
#pragma unroll
        for (int i = 0; i < 4; ++i)
#pragma unroll
            for (int j = 0; j < 4; ++j)
                acc[i][j] = __builtin_amdgcn_mfma_f32_16x16x32_bf16(a[i], b[j], acc[i][j], 0, 0, 0);
        __syncthreads();
    }

    const int rq = lane >> 4;
    if (MODE == 0) {
        const int relid = bcol / cols_per_rel;
        const float* nsr = scale_or_bias + (size_t)relid * Nnodes;
#pragma unroll
        for (int i = 0; i < 4; ++i) {
            int rbase = brow + wr * 64 + i * 16 + rq * 4;
            float sc[4];
#pragma unroll
            for (int t = 0; t < 4; ++t) {
                int row = rbase + t;
                sc[t] = (row < M) ? nsr[row] : 0.f;
            }
#pragma unroll
            for (int j = 0; j < 4; ++j) {
                int col = bcol + wc * 64 + j * 16 + rl;
#pragma unroll
                for (int t = 0; t < 4; ++t) {
                    int row = rbase + t;
                    if (row < M) C[(size_t)row * Nout + col] = f2bf(acc[i][j][t] * sc[t]);
                }
            }
        }
    } else {
#pragma unroll
        for (int i = 0; i < 4; ++i) {
            int rbase = brow + wr * 64 + i * 16 + rq * 4;
#pragma unroll
            for (int j = 0; j < 4; ++j) {
                int col = bcol + wc * 64 + j * 16 + rl;
                float bb = scale_or_bias[col];
#pragma unroll
                for (int t = 0; t < 4; ++t) {
                    int row = rbase + t;
                    if (row < M) C[(size_t)row * Nout + col] = f2bf(fmaxf(acc[i][j][t] + bb, 0.f));
                }
            }
        }
    }
}

// ---- gathers ---------------------------------------------------------------

// layer 1 aggregate-first: one wave per (node, relation); HALF-WAVE per edge.
__global__ void gather1_agg(const unsigned short* __restrict__ x_bf,
                            const int* __restrict__ rp, const long long* __restrict__ e_pack,
                            const float* __restrict__ ndst,
                            unsigned short* __restrict__ agg4, int N) {
    long w = (blockIdx.x * (long)blockDim.x + threadIdx.x) >> 6;
    int d = (int)(w >> 2);
    if (d >= N) return;
    int r = (int)(w & 3);
    int lane = threadIdx.x & 63;
    int h = lane >> 5, l = lane & 31;
    int beg = rp[(size_t)r * N + d], end = rp[(size_t)r * N + d + 1];
    float acc0[8] = {}, acc1[8] = {};
    int e = beg + h;
    for (; e + 2 < end; e += 4) {     // this half's edges: e, e+2
        unsigned long long p0 = (unsigned long long)e_pack[e];
        unsigned long long p1 = (unsigned long long)e_pack[e + 2];
        int s0 = (int)(unsigned int)p0;
        int s1 = (int)(unsigned int)p1;
        ushort8 v0 = *(const ushort8*)(x_bf + (size_t)s0 * DIN + l * 8);
        ushort8 v1 = *(const ushort8*)(x_bf + (size_t)s1 * DIN + l * 8);
        float ns0 = __uint_as_float((unsigned int)(p0 >> 32));
        float ns1 = __uint_as_float((unsigned int)(p1 >> 32));
#pragma unroll
        for (int j = 0; j < 8; ++j) {
            acc0[j] += ns0 * bf2f(v0[j]);
            acc1[j] += ns1 * bf2f(v1[j]);
        }
    }
    if (e < end) {
        unsigned long long p0 = (unsigned long long)e_pack[e];
        int s0 = (int)(unsigned int)p0;
        ushort8 v0 = *(const ushort8*)(x_bf + (size_t)s0 * DIN + l * 8);
        float ns0 = __uint_as_float((unsigned int)(p0 >> 32));
#pragma unroll
        for (int j = 0; j < 8; ++j) acc0[j] += ns0 * bf2f(v0[j]);
    }
    float nd = ndst[(size_t)r * N + d];
    ushort8 o;
#pragma unroll
    for (int j = 0; j < 8; ++j) {
        float v = acc0[j] + acc1[j];
        v += __shfl_xor(v, 32);
        o[j] = f2bf(nd * v);
    }
    if (h == 0)
        __builtin_nontemporal_store(o, (ushort8*)(agg4 + (size_t)d * (RELS * DIN) + r * DIN + l * 8));
}

// layer 2 project-first: one wave per dst node; HALF-WAVE per edge (8B loads).
__global__ void gather2_fused(const unsigned short* __restrict__ hw4,
                              const int* __restrict__ rp, const long long* __restrict__ e_pack,
                              const float* __restrict__ ndst, const float* __restrict__ b2s,
                              float* __restrict__ out, int N) {
    int wid = (int)((blockIdx.x * (long)blockDim.x + threadIdx.x) >> 6);
    if (wid >= N) return;
    int lane = threadIdx.x & 63;
    int h = lane >> 5, l = lane & 31;
    float oacc[4] = {};
#pragma unroll
    for (int r = 0; r < RELS; ++r) {
        int beg = rp[(size_t)r * N + wid], end = rp[(size_t)r * N + wid + 1];
        float acc0[4] = {}, acc1[4] = {};
        int e = beg + h;
        for (; e + 2 < end; e += 4) {
            int s0 = (int)(unsigned int)(unsigned long long)e_pack[e];
            int s1 = (int)(unsigned int)(unsigned long long)e_pack[e + 2];
            ushort4 v0 = *(const ushort4*)(hw4 + (size_t)s0 * (RELS * DOUT) + r * DOUT + l * 4);
            ushort4 v1 = *(const ushort4*)(hw4 + (size_t)s1 * (RELS * DOUT) + r * DOUT + l * 4);
            acc0[0] += bf2f(v0.x); acc0[1] += bf2f(v0.y); acc0[2] += bf2f(v0.z); acc0[3] += bf2f(v0.w);
            acc1[0] += bf2f(v1.x); acc1[1] += bf2f(v1.y); acc1[2] += bf2f(v1.z); acc1[3] += bf2f(v1.w);
        }
        if (e < end) {
            int s0 = (int)(unsigned int)(unsigned long long)e_pack[e];
            ushort4 v0 = *(const ushort4*)(hw4 + (size_t)s0 * (RELS * DOUT) + r * DOUT + l * 4);
            acc0[0] += bf2f(v0.x); acc0[1] += bf2f(v0.y); acc0[2] += bf2f(v0.z); acc0[3] += bf2f(v0.w);
        }
        float nd = ndst[(size_t)r * N + wid];
#pragma unroll
        for (int j = 0; j < 4; ++j) oacc[j] += nd * (acc0[j] + acc1[j]);
    }
#pragma unroll
    for (int j = 0; j < 4; ++j) oacc[j] += __shfl_xor(oacc[j], 32);
    if (h == 0) {
        f32x4 o;
        o[0] = oacc[0] + b2s[l * 4 + 0];
        o[1] = oacc[1] + b2s[l * 4 + 1];
        o[2] = oacc[2] + b2s[l * 4 + 2];
        o[3] = oacc[3] + b2s[l * 4 + 3];
        __builtin_nontemporal_store(o, (f32x4*)(out + (size_t)wid * DOUT + l * 4));
    }
}

// ---- launch ------------------------------------------------------------------

extern "C" void kernel_launch(void* const* d_in, const int* in_sizes, int n_in,
                              void* d_out, int out_size, void* d_ws, size_t ws_size,
                              hipStream_t stream) {
    const float* x   = (const float*)d_in[0];
    const int*   src = (const int*)d_in[1];
    const int*   dst = (const int*)d_in[2];
    const float* W1  = (const float*)d_in[3];
    const float* b1  = (const float*)d_in[4];
    const float* W2  = (const float*)d_in[5];
    const float* b2  = (const float*)d_in[6];
    float* out = (float*)d_out;

    const int N = in_sizes[0] / DIN;       // 100000
    const int E = in_sizes[1] / RELS;      // 400000
    const int RN = RELS * N;

    // Workspace layout
    char* p = (char*)d_ws;
    int*   cnt_src = (int*)p;    p += (size_t)RN * sizeof(int);
    int*   cnt_dst = (int*)p;    p += (size_t)RN * sizeof(int);       // contiguous after cnt_src
    float* nsrc    = (float*)p;  p += (size_t)RN * sizeof(float);
    float* ndst    = (float*)p;  p += (size_t)RN * sizeof(float);     // contiguous after nsrc
    int*   row_ptr = (int*)p;    p += ((size_t)RN + 16) * sizeof(int);
    int*   rank    = (int*)p;    p += (size_t)RELS * E * sizeof(int);
    long long* e_pack = (long long*)p; p += (size_t)RELS * E * sizeof(long long);
    int*   blk_sums= (int*)p;    p += 2048 * sizeof(int);
    float* b1s     = (float*)p;  p += DHID * sizeof(float);
    float* b2s     = (float*)p;  p += DOUT * sizeof(float);
    unsigned short* x_bf = (unsigned short*)p; p += (size_t)N * DIN * sizeof(short);
    unsigned short* w1t  = (unsigned short*)p; p += (size_t)RELS * DIN * DHID * sizeof(short);
    unsigned short* w2t  = (unsigned short*)p; p += (size_t)RELS * DHID * DOUT * sizeof(short);
    unsigned short* h_bf = (unsigned short*)p; p += (size_t)N * DHID * sizeof(short);
    unsigned short* agg4 = (unsigned short*)p; p += (size_t)N * RELS * DIN * sizeof(short);
    unsigned short* hw4  = agg4;   // alias: agg4 dead after gemm1

    // 1) memset counters, then merged hist(+rank) || prep (NT streams)
    hipMemsetAsync(cnt_src, 0, (size_t)2 * RN * sizeof(int), stream);
    const long n8x = (long)N * DIN / 8;
    {
        const int HB = (RELS * E + 255) / 256;
        long preptot = n8x + RELS * DIN * DHID + RELS * DHID * DOUT + DHID + DOUT;
        int PB = (int)((preptot + 255) / 256);
        hist_prep<<<HB + PB, 256, 0, stream>>>(
            src, dst, cnt_src, cnt_dst, rank, E, N, HB,
            x, W1, W2, b1, b2, x_bf, w1t, w2t, b1s, b2s, n8x);
    }

    // 2) merged scan_block || norm, then scan_sums, scan_add
    const int nscan = (RN + 255) / 256;
    {
        long nnorm = (long)2 * RN;
        int NB = (int)((nnorm + 255) / 256);
        scan_norm<<<nscan + NB, 256, 0, stream>>>(
            cnt_dst, row_ptr, blk_sums, RN, nscan, cnt_src, nsrc, nnorm);
    }
    scan_sums<<<1, 256, 0, stream>>>(blk_sums, nscan);
    scan_add<<<nscan, 256, 0, stream>>>(row_ptr, blk_sums, RN, RELS * E);

    // 3) atomic-free fill
    {
        int total = RELS * E;
        fill_kernel<<<(total + 255) / 256, 256, 0, stream>>>(
            src, dst, nsrc, row_ptr, rank, e_pack, E, N);
    }

    const int gx = (N + 127) / 128;

    // 4) layer 1 aggregate-first: gather x -> agg4 [N][1024], then concat GEMM
    //    [N,1024]@[1024,256] with bias+relu epilogue -> h_bf
    {
        long waves = (long)RELS * N;
        int blocks = (int)((waves + 3) / 4);
        gather1_agg<<<blocks, 256, 0, stream>>>(x_bf, row_ptr, e_pack, ndst, agg4, N);
        dim3 grid(gx, DHID / 128);
        gemm_bf16<1><<<grid, 256, 0, stream>>>(agg4, w1t, h_bf, N, DHID, RELS * DIN, b1s, 0, N);
    }

    // 5) layer 2 project-first: concat GEMM (Nout=512, nsrc epilogue) + gather
    {
        dim3 grid(gx, (RELS * DOUT) / 128);
        gemm_bf16<0><<<grid, 256, 0, stream>>>(h_bf, w2t, hw4, N, RELS * DOUT, DHID, nsrc, DOUT, N);
        int gblocks = (N + 3) / 4;
        gather2_fused<<<gblocks, 256, 0, stream>>>(hw4, row_ptr, e_pack, ndst, b2s, out, N);
    }
}

// Round 13
// 738.275 us; speedup vs baseline: 1.1007x; 1.1007x over previous
//
#include <hip/hip_runtime.h>

// RGCN: 2-layer hetero GraphConv, R=4 relations.
// R1: CSR gather. R2: bf16 MFMA GEMM. R3: concat-GEMM + fused gathers.
// R4: layer-1 aggregate-first. R6: e_pack int2 stream. R7: half-wave gathers.
// R8: NT-store gather outputs (779us best). R9-R11 REGRESSED: hist+prep merge
// bad (returning-atomic + stream co-residency); NT-store on e_pack starved
// gather1's L2 (176->197us). R12: R8 base + rank-from-hist (atomic-free fill,
// plain e_pack store) + norm folded into scan launch. NT only on outputs not
// read by the next kernel.

#define RELS 4
#define DIN 256
#define DHID 256
#define DOUT 128

typedef short short8 __attribute__((ext_vector_type(8)));
typedef unsigned short ushort8 __attribute__((ext_vector_type(8)));
typedef float f32x4 __attribute__((ext_vector_type(4)));

// ---- helpers --------------------------------------------------------------

__device__ __forceinline__ unsigned short f2bf(float f) {
    unsigned int u = __float_as_uint(f);
    u += 0x7FFFu + ((u >> 16) & 1u);   // round-to-nearest-even
    return (unsigned short)(u >> 16);
}
__device__ __forceinline__ float bf2f(unsigned short u) {
    return __uint_as_float(((unsigned int)u) << 16);
}

// ---- CSR build --------------------------------------------------------------

// histogram src/dst; dst atomic's return value = edge's rank within its
// (rel,dst) segment -> enables atomic-free fill.
__global__ void hist_kernel(const int* __restrict__ src, const int* __restrict__ dst,
                            int* __restrict__ cnt_src, int* __restrict__ cnt_dst,
                            int* __restrict__ rank, int E, int N) {
    int i = blockIdx.x * blockDim.x + threadIdx.x;
    if (i >= RELS * E) return;
    int r = i / E;
    atomicAdd(cnt_src + (size_t)r * N + src[i], 1);
    int rk = atomicAdd(cnt_dst + (size_t)r * N + dst[i], 1);
    rank[i] = rk;
}

// scan_block (SB blocks) || norm (remaining blocks) — both depend only on hist
__global__ void scan_norm(const int* __restrict__ counts, int* __restrict__ out,
                          int* __restrict__ blk_sums, int n, int SB,
                          const int* __restrict__ cnt, float* __restrict__ nrm, long nnorm) {
    if ((int)blockIdx.x < SB) {
        __shared__ int sh[256];
        int i = blockIdx.x * 256 + threadIdx.x;
        int v = (i < n) ? counts[i] : 0;
        sh[threadIdx.x] = v;
        __syncthreads();
#pragma unroll
        for (int off = 1; off < 256; off <<= 1) {
            int t = (threadIdx.x >= off) ? sh[threadIdx.x - off] : 0;
            __syncthreads();
            sh[threadIdx.x] += t;
            __syncthreads();
        }
        if (i < n) out[i] = sh[threadIdx.x] - v;
        if (threadIdx.x == 255) blk_sums[blockIdx.x] = sh[255];
    } else {
        long i = (long)(blockIdx.x - SB) * 256 + threadIdx.x;
        if (i < nnorm) nrm[i] = rsqrtf(fmaxf((float)cnt[i], 1.0f));
    }
}

__global__ void scan_sums(int* __restrict__ bs, int nb) {
    __shared__ int sh[256];
    __shared__ int carry;
    if (threadIdx.x == 0) carry = 0;
    __syncthreads();
    for (int base = 0; base < nb; base += 256) {
        int i = base + threadIdx.x;
        int v = (i < nb) ? bs[i] : 0;
        sh[threadIdx.x] = v;
        __syncthreads();
#pragma unroll
        for (int off = 1; off < 256; off <<= 1) {
            int t = (threadIdx.x >= off) ? sh[threadIdx.x - off] : 0;
            __syncthreads();
            sh[threadIdx.x] += t;
            __syncthreads();
        }
        if (i < nb) bs[i] = sh[threadIdx.x] - v + carry;  // exclusive
        int tot = sh[255];
        __syncthreads();
        if (threadIdx.x == 255) carry += tot;
        __syncthreads();
    }
}

__global__ void scan_add(int* __restrict__ out, const int* __restrict__ blk_sums,
                         int n, int total) {
    int i = blockIdx.x * 256 + threadIdx.x;
    if (i < n) out[i] += blk_sums[blockIdx.x];
    if (i == n - 1) out[n] = total;
}

// atomic-free fill: pos = row_ptr[r][dst] + rank. Plain stores (e_pack is read
// by the very next kernels — keep it L2-resident).
__global__ void fill_kernel(const int* __restrict__ src, const int* __restrict__ dst,
                            const float* __restrict__ nsrc, const int* __restrict__ row_ptr,
                            const int* __restrict__ rank, int2* __restrict__ e_pack,
                            int E, int N) {
    int i = blockIdx.x * blockDim.x + threadIdx.x;
    if (i >= RELS * E) return;
    int r = i / E;
    int s = src[i];
    int pos = row_ptr[(size_t)r * N + dst[i]] + rank[i];
    e_pack[pos] = make_int2(s, __float_as_int(nsrc[(size_t)r * N + s]));
}

// ---- fused prep: x->bf16, W1^T, W2^T, bias sums (separate launch, R8 form) --

__global__ void prep_fused(const float* __restrict__ x, const float* __restrict__ W1,
                           const float* __restrict__ W2, const float* __restrict__ b1,
                           const float* __restrict__ b2,
                           unsigned short* __restrict__ x_bf, unsigned short* __restrict__ w1t,
                           unsigned short* __restrict__ w2t,
                           float* __restrict__ b1s, float* __restrict__ b2s, long n8x) {
    const int T1 = RELS * DIN * DHID;
    const int T2 = RELS * DHID * DOUT;
    long i = blockIdx.x * (long)blockDim.x + threadIdx.x;
    if (i < n8x) {
        const float4* ip = (const float4*)(x + i * 8);
        float4 v0 = ip[0], v1 = ip[1];
        ushort4 o0 = make_ushort4(f2bf(v0.x), f2bf(v0.y), f2bf(v0.z), f2bf(v0.w));
        ushort4 o1 = make_ushort4(f2bf(v1.x), f2bf(v1.y), f2bf(v1.z), f2bf(v1.w));
        ushort4* op = (ushort4*)(x_bf + i * 8);
        op[0] = o0; op[1] = o1;
    } else if (i < n8x + T1) {
        int j = (int)(i - n8x);
        int r = j / (DIN * DHID);
        int rem = j - r * (DIN * DHID);
        int k = rem / DHID, n = rem - k * DHID;
        w1t[(size_t)n * (RELS * DIN) + r * DIN + k] = f2bf(W1[j]);
    } else if (i < n8x + T1 + T2) {
        int j = (int)(i - n8x - T1);
        int r = j / (DHID * DOUT);
        int rem = j - r * (DHID * DOUT);
        int k = rem / DOUT, n = rem - k * DOUT;
        w2t[((size_t)r * DOUT + n) * DHID + k] = f2bf(W2[j]);
    } else if (i < n8x + T1 + T2 + DHID + DOUT) {
        int c = (int)(i - n8x - T1 - T2);
        if (c < DHID) {
            b1s[c] = b1[c] + b1[DHID + c] + b1[2 * DHID + c] + b1[3 * DHID + c];
        } else {
            int cc = c - DHID;
            b2s[cc] = b2[cc] + b2[DOUT + cc] + b2[2 * DOUT + cc] + b2[3 * DOUT + cc];
        }
    }
}

// ---- bf16 MFMA GEMM ---------------------------------------------------------
// BM=BN=128, BK=32, 256 threads (4 waves 2x2), 4x4 frags of 16x16x32/wave.
// LDS [128][32] bf16 per operand, XOR chunk swizzle (both-sides involution).
// MODE 0: C = bf16( acc * nsrc[rel][row] )          (layer-2 project-first)
// MODE 1: C = bf16( relu(acc + bias[col]) )         (layer-1 agg-first)

__device__ __forceinline__ void gload_lds16(const void* g, void* l) {
    __builtin_amdgcn_global_load_lds(
        (const __attribute__((address_space(1))) void*)g,
        (__attribute__((address_space(3))) void*)l, 16, 0, 0);
}

template <int MODE>
__global__ __launch_bounds__(256) void gemm_bf16(
    const unsigned short* __restrict__ A, const unsigned short* __restrict__ Bt,
    unsigned short* __restrict__ C, int M, int Nout, int K,
    const float* __restrict__ scale_or_bias, int cols_per_rel, int Nnodes) {
    __shared__ unsigned short smA[128 * 32];
    __shared__ unsigned short smB[128 * 32];
    const int tid = threadIdx.x;
    const int lane = tid & 63;
    const int wid = tid >> 6;
    const int wr = wid >> 1, wc = wid & 1;
    const int brow = blockIdx.x * 128, bcol = blockIdx.y * 128;

    f32x4 acc[4][4] = {};

    const int s = lane >> 4;
    const int rl = lane & 15;

    for (int k0 = 0; k0 < K; k0 += 32) {
#pragma unroll
        for (int q = 0; q < 2; ++q) {
            int c = q * 256 + tid;
            int cl = c ^ ((c >> 3) & 3);
            int row = cl >> 2, slot = cl & 3;
            int ga = brow + row; ga = ga < M ? ga : M - 1;
            size_t ldsoff = (size_t)(q * 256 + (tid & ~63)) * 16;
            gload_lds16(A + (size_t)ga * K + k0 + slot * 8, (char*)smA + ldsoff);
            gload_lds16(Bt + (size_t)(bcol + row) * K + k0 + slot * 8, (char*)smB + ldsoff);
        }
        asm volatile("s_waitcnt vmcnt(0)" ::: "memory");
        __syncthreads();

        short8 a[4], b[4];
#pragma unroll
        for (int i = 0; i < 4; ++i) {
            int r = wr * 64 + i * 16 + rl;
            int ch = r * 4 + (s ^ ((r >> 1) & 3));
            a[i] = *(const short8*)((const char*)smA + ch * 16);
        }
#pragma unroll
        for (int j = 0; j < 4; ++j) {
            int r = wc * 64 + j * 16 + rl;
            int ch = r * 4 + (s ^ ((r >> 1) & 3));
            b[j] = *(const short8*)((const char*)smB + ch * 16);
        }
#pragma unroll
        for (int i = 0; i < 4; ++i)
#pragma unroll
            for (int j = 0; j < 4; ++j)
                acc[i][j] = __builtin_amdgcn_mfma_f32_16x16x32_bf16(a[i], b[j], acc[i][j], 0, 0, 0);
        __syncthreads();
    }

    const int rq = lane >> 4;
    if (MODE == 0) {
        const int relid = bcol / cols_per_rel;
        const float* nsr = scale_or_bias + (size_t)relid * Nnodes;
#pragma unroll
        for (int i = 0; i < 4; ++i) {
            int rbase = brow + wr * 64 + i * 16 + rq * 4;
            float sc[4];
#pragma unroll
            for (int t = 0; t < 4; ++t) {
                int row = rbase + t;
                sc[t] = (row < M) ? nsr[row] : 0.f;
            }
#pragma unroll
            for (int j = 0; j < 4; ++j) {
                int col = bcol + wc * 64 + j * 16 + rl;
#pragma unroll
                for (int t = 0; t < 4; ++t) {
                    int row = rbase + t;
                    if (row < M) C[(size_t)row * Nout + col] = f2bf(acc[i][j][t] * sc[t]);
                }
            }
        }
    } else {
#pragma unroll
        for (int i = 0; i < 4; ++i) {
            int rbase = brow + wr * 64 + i * 16 + rq * 4;
#pragma unroll
            for (int j = 0; j < 4; ++j) {
                int col = bcol + wc * 64 + j * 16 + rl;
                float bb = scale_or_bias[col];
#pragma unroll
                for (int t = 0; t < 4; ++t) {
                    int row = rbase + t;
                    if (row < M) C[(size_t)row * Nout + col] = f2bf(fmaxf(acc[i][j][t] + bb, 0.f));
                }
            }
        }
    }
}

// ---- gathers (byte-identical to R8) -----------------------------------------

// layer 1 aggregate-first: one wave per (node, relation); HALF-WAVE per edge.
__global__ void gather1_agg(const unsigned short* __restrict__ x_bf,
                            const int* __restrict__ rp, const int2* __restrict__ e_pack,
                            const float* __restrict__ ndst,
                            unsigned short* __restrict__ agg4, int N) {
    long w = (blockIdx.x * (long)blockDim.x + threadIdx.x) >> 6;
    int d = (int)(w >> 2);
    if (d >= N) return;
    int r = (int)(w & 3);
    int lane = threadIdx.x & 63;
    int h = lane >> 5, l = lane & 31;
    int beg = rp[(size_t)r * N + d], end = rp[(size_t)r * N + d + 1];
    float acc0[8] = {}, acc1[8] = {};
    int e = beg + h;
    for (; e + 2 < end; e += 4) {     // this half's edges: e, e+2
        int2 p0 = e_pack[e];
        int2 p1 = e_pack[e + 2];
        ushort8 v0 = *(const ushort8*)(x_bf + (size_t)p0.x * DIN + l * 8);
        ushort8 v1 = *(const ushort8*)(x_bf + (size_t)p1.x * DIN + l * 8);
        float ns0 = __int_as_float(p0.y);
        float ns1 = __int_as_float(p1.y);
#pragma unroll
        for (int j = 0; j < 8; ++j) {
            acc0[j] += ns0 * bf2f(v0[j]);
            acc1[j] += ns1 * bf2f(v1[j]);
        }
    }
    if (e < end) {
        int2 p0 = e_pack[e];
        ushort8 v0 = *(const ushort8*)(x_bf + (size_t)p0.x * DIN + l * 8);
        float ns0 = __int_as_float(p0.y);
#pragma unroll
        for (int j = 0; j < 8; ++j) acc0[j] += ns0 * bf2f(v0[j]);
    }
    float nd = ndst[(size_t)r * N + d];
    ushort8 o;
#pragma unroll
    for (int j = 0; j < 8; ++j) {
        float v = acc0[j] + acc1[j];
        v += __shfl_xor(v, 32);
        o[j] = f2bf(nd * v);
    }
    if (h == 0)
        __builtin_nontemporal_store(o, (ushort8*)(agg4 + (size_t)d * (RELS * DIN) + r * DIN + l * 8));
}

// layer 2 project-first: one wave per dst node; HALF-WAVE per edge (8B loads).
__global__ void gather2_fused(const unsigned short* __restrict__ hw4,
                              const int* __restrict__ rp, const int2* __restrict__ e_pack,
                              const float* __restrict__ ndst, const float* __restrict__ b2s,
                              float* __restrict__ out, int N) {
    int wid = (int)((blockIdx.x * (long)blockDim.x + threadIdx.x) >> 6);
    if (wid >= N) return;
    int lane = threadIdx.x & 63;
    int h = lane >> 5, l = lane & 31;
    float oacc[4] = {};
#pragma unroll
    for (int r = 0; r < RELS; ++r) {
        int beg = rp[(size_t)r * N + wid], end = rp[(size_t)r * N + wid + 1];
        float acc0[4] = {}, acc1[4] = {};
        int e = beg + h;
        for (; e + 2 < end; e += 4) {
            int s0 = e_pack[e].x;
            int s1 = e_pack[e + 2].x;
            ushort4 v0 = *(const ushort4*)(hw4 + (size_t)s0 * (RELS * DOUT) + r * DOUT + l * 4);
            ushort4 v1 = *(const ushort4*)(hw4 + (size_t)s1 * (RELS * DOUT) + r * DOUT + l * 4);
            acc0[0] += bf2f(v0.x); acc0[1] += bf2f(v0.y); acc0[2] += bf2f(v0.z); acc0[3] += bf2f(v0.w);
            acc1[0] += bf2f(v1.x); acc1[1] += bf2f(v1.y); acc1[2] += bf2f(v1.z); acc1[3] += bf2f(v1.w);
        }
        if (e < end) {
            int s0 = e_pack[e].x;
            ushort4 v0 = *(const ushort4*)(hw4 + (size_t)s0 * (RELS * DOUT) + r * DOUT + l * 4);
            acc0[0] += bf2f(v0.x); acc0[1] += bf2f(v0.y); acc0[2] += bf2f(v0.z); acc0[3] += bf2f(v0.w);
        }
        float nd = ndst[(size_t)r * N + wid];
#pragma unroll
        for (int j = 0; j < 4; ++j) oacc[j] += nd * (acc0[j] + acc1[j]);
    }
#pragma unroll
    for (int j = 0; j < 4; ++j) oacc[j] += __shfl_xor(oacc[j], 32);
    if (h == 0) {
        f32x4 o;
        o[0] = oacc[0] + b2s[l * 4 + 0];
        o[1] = oacc[1] + b2s[l * 4 + 1];
        o[2] = oacc[2] + b2s[l * 4 + 2];
        o[3] = oacc[3] + b2s[l * 4 + 3];
        __builtin_nontemporal_store(o, (f32x4*)(out + (size_t)wid * DOUT + l * 4));
    }
}

// ---- launch ------------------------------------------------------------------

extern "C" void kernel_launch(void* const* d_in, const int* in_sizes, int n_in,
                              void* d_out, int out_size, void* d_ws, size_t ws_size,
                              hipStream_t stream) {
    const float* x   = (const float*)d_in[0];
    const int*   src = (const int*)d_in[1];
    const int*   dst = (const int*)d_in[2];
    const float* W1  = (const float*)d_in[3];
    const float* b1  = (const float*)d_in[4];
    const float* W2  = (const float*)d_in[5];
    const float* b2  = (const float*)d_in[6];
    float* out = (float*)d_out;

    const int N = in_sizes[0] / DIN;       // 100000
    const int E = in_sizes[1] / RELS;      // 400000
    const int RN = RELS * N;

    // Workspace layout
    char* p = (char*)d_ws;
    int*   cnt_src = (int*)p;    p += (size_t)RN * sizeof(int);
    int*   cnt_dst = (int*)p;    p += (size_t)RN * sizeof(int);       // contiguous after cnt_src
    float* nsrc    = (float*)p;  p += (size_t)RN * sizeof(float);
    float* ndst    = (float*)p;  p += (size_t)RN * sizeof(float);     // contiguous after nsrc
    int*   row_ptr = (int*)p;    p += ((size_t)RN + 16) * sizeof(int);
    int*   rank    = (int*)p;    p += (size_t)RELS * E * sizeof(int);
    int2*  e_pack  = (int2*)p;   p += (size_t)RELS * E * sizeof(int2);
    int*   blk_sums= (int*)p;    p += 2048 * sizeof(int);
    float* b1s     = (float*)p;  p += DHID * sizeof(float);
    float* b2s     = (float*)p;  p += DOUT * sizeof(float);
    unsigned short* x_bf = (unsigned short*)p; p += (size_t)N * DIN * sizeof(short);
    unsigned short* w1t  = (unsigned short*)p; p += (size_t)RELS * DIN * DHID * sizeof(short);
    unsigned short* w2t  = (unsigned short*)p; p += (size_t)RELS * DHID * DOUT * sizeof(short);
    unsigned short* h_bf = (unsigned short*)p; p += (size_t)N * DHID * sizeof(short);
    unsigned short* agg4 = (unsigned short*)p; p += (size_t)N * RELS * DIN * sizeof(short);
    unsigned short* hw4  = agg4;   // alias: agg4 dead after gemm1

    // 0) fused prep (separate launch — merging with hist regressed, R10/R11)
    const long n8x = (long)N * DIN / 8;
    {
        long tot = n8x + RELS * DIN * DHID + RELS * DHID * DOUT + DHID + DOUT;
        prep_fused<<<(int)((tot + 255) / 256), 256, 0, stream>>>(
            x, W1, W2, b1, b2, x_bf, w1t, w2t, b1s, b2s, n8x);
    }

    // 1) degree histograms + rank capture
    hipMemsetAsync(cnt_src, 0, (size_t)2 * RN * sizeof(int), stream);
    {
        int total = RELS * E;
        hist_kernel<<<(total + 255) / 256, 256, 0, stream>>>(
            src, dst, cnt_src, cnt_dst, rank, E, N);
    }

    // 2) scan_block || norm, then scan_sums, scan_add
    const int nscan = (RN + 255) / 256;
    {
        long nnorm = (long)2 * RN;
        int NB = (int)((nnorm + 255) / 256);
        scan_norm<<<nscan + NB, 256, 0, stream>>>(
            cnt_dst, row_ptr, blk_sums, RN, nscan, cnt_src, nsrc, nnorm);
    }
    scan_sums<<<1, 256, 0, stream>>>(blk_sums, nscan);
    scan_add<<<nscan, 256, 0, stream>>>(row_ptr, blk_sums, RN, RELS * E);

    // 3) atomic-free fill
    {
        int total = RELS * E;
        fill_kernel<<<(total + 255) / 256, 256, 0, stream>>>(
            src, dst, nsrc, row_ptr, rank, e_pack, E, N);
    }

    const int gx = (N + 127) / 128;

    // 4) layer 1 aggregate-first: gather x -> agg4 [N][1024], then concat GEMM
    //    [N,1024]@[1024,256] with bias+relu epilogue -> h_bf
    {
        long waves = (long)RELS * N;
        int blocks = (int)((waves + 3) / 4);
        gather1_agg<<<blocks, 256, 0, stream>>>(x_bf, row_ptr, e_pack, ndst, agg4, N);
        dim3 grid(gx, DHID / 128);
        gemm_bf16<1><<<grid, 256, 0, stream>>>(agg4, w1t, h_bf, N, DHID, RELS * DIN, b1s, 0, N);
    }

    // 5) layer 2 project-first: concat GEMM (Nout=512, nsrc epilogue) + gather
    {
        dim3 grid(gx, (RELS * DOUT) / 128);
        gemm_bf16<0><<<grid, 256, 0, stream>>>(h_bf, w2t, hw4, N, RELS * DOUT, DHID, nsrc, DOUT, N);
        int gblocks = (N + 3) / 4;
        gather2_fused<<<gblocks, 256, 0, stream>>>(hw4, row_ptr, e_pack, ndst, b2s, out, N);
    }
}